// Round 16
// baseline (172.556 us; speedup 1.0000x reference)
//
#include <hip/hip_runtime.h>
#include <hip/hip_bf16.h>
#include <cstdint>
#include <cstddef>

#define NV    8192   // nodes
#define KIN   512    // in features
#define MOUT  128    // out features
#define LOG2E 1.4426950408889634f

typedef __attribute__((ext_vector_type(4))) float f32x4;
typedef __attribute__((ext_vector_type(8))) short short8;

__device__ __forceinline__ float elu1(float x) { return x > 0.f ? x : expm1f(x); }

__device__ __forceinline__ unsigned int pkbf2(float a, float b) {
  union { __hip_bfloat162 h2; unsigned int u; } r;
  r.h2 = __float22bfloat162_rn(make_float2(a, b));
  return r.u;
}

// ---------------- kernel 1: wh1/wh2 (log2-scaled) + fragB (bf16, MFMA-fragment order) ----------------
// 16-row blocks (512 total, >=2/CU). fragB element (j=jt*64+ks*32+lg*8+e, c=cgf*16+l15).
__global__ __launch_bounds__(256) void k_wh(const float* __restrict__ h,
                                            const float* __restrict__ w,
                                            const float* __restrict__ a1,
                                            const float* __restrict__ a2,
                                            unsigned short* __restrict__ fragB,
                                            float* __restrict__ wh1,
                                            float* __restrict__ wh2,
                                            int* __restrict__ cnt) {
  __shared__ __align__(16) float hT[64][18];    // [k][row], 16 rows + 2 pad
  __shared__ __align__(16) float wT[64][128];   // [k][col]
  const int t = threadIdx.x;
  const int row0 = blockIdx.x * 16;
  const int hrow = t & 15, hkq = t >> 4;        // h-load: row, k-quad
  const int wc = t >> 1, whalf = t & 1;         // w-load
  const int cg = t & 31, rg = t >> 5;           // gemm: col-group(4), row-group(2)
  const int c0 = cg * 4, r0 = rg * 2;
  float acc[2][4] = {};

  if (blockIdx.x == 0 && t < 128) cnt[t] = 0;   // reset combine counters each launch

  for (int kt = 0; kt < 8; ++kt) {
    const int k0 = kt * 64;
    __syncthreads();
    {
      const float4 hv = *(const float4*)&h[(size_t)(row0 + hrow) * KIN + k0 + hkq * 4];
      hT[hkq * 4 + 0][hrow] = hv.x;
      hT[hkq * 4 + 1][hrow] = hv.y;
      hT[hkq * 4 + 2][hrow] = hv.z;
      hT[hkq * 4 + 3][hrow] = hv.w;
    }
#pragma unroll
    for (int mv = 0; mv < 8; ++mv) {
      const float4 wv4 = *(const float4*)&w[(size_t)wc * KIN + k0 + whalf * 32 + mv * 4];
      wT[whalf * 32 + mv * 4 + 0][wc] = wv4.x;
      wT[whalf * 32 + mv * 4 + 1][wc] = wv4.y;
      wT[whalf * 32 + mv * 4 + 2][wc] = wv4.z;
      wT[whalf * 32 + mv * 4 + 3][wc] = wv4.w;
    }
    __syncthreads();
#pragma unroll 8
    for (int kk = 0; kk < 64; ++kk) {
      const float2 hv = *(const float2*)&hT[kk][r0];
      const float4 wv4 = *(const float4*)&wT[kk][c0];
      const float hvv[2] = {hv.x, hv.y};
      const float wvv[4] = {wv4.x, wv4.y, wv4.z, wv4.w};
#pragma unroll
      for (int i = 0; i < 2; ++i)
#pragma unroll
        for (int j = 0; j < 4; ++j)
          acc[i][j] = fmaf(hvv[i], wvv[j], acc[i][j]);
    }
  }

  // fragB store straight from accumulators.
  // local row lr = rg*2+i -> j = row0+lr. jt=row0>>6, ks=(row0>>5)&1 fixed per block.
  // R15 BUG FIX: lg reduces j modulo the 32-row ks-block -> use (row0 & 31), NOT & 63
  // (&63 included the ks bit: blocks with row0%64 in {32,48} got lg=4..7, overflowing
  // the lane field into the next ks/cgf fragment -> scattered B values, absmax 4.9e-2).
  {
    const size_t jt = (size_t)(row0 >> 6);
    const int ks = (row0 >> 5) & 1;
    const int lg = (((row0 & 31) + rg * 2) >> 3);   // 0..3
    const int cgf = cg >> 2;
    unsigned int* fB32 = (unsigned int*)fragB;
    const size_t ubase = (((jt * 8 + cgf) * 2 + ks) * 64 + lg * 16) * 4 + (rg & 3);
#pragma unroll
    for (int j = 0; j < 4; ++j) {
      const int l15 = (cg & 3) * 4 + j;
      fB32[ubase + (size_t)l15 * 4] = pkbf2(acc[0][j], acc[1][j]);
    }
  }

  const float4 a1v = *(const float4*)&a1[c0];
  const float4 a2v = *(const float4*)&a2[c0];
#pragma unroll
  for (int i = 0; i < 2; ++i) {
    float s1 = acc[i][0] * a1v.x + acc[i][1] * a1v.y + acc[i][2] * a1v.z + acc[i][3] * a1v.w;
    float s2 = acc[i][0] * a2v.x + acc[i][1] * a2v.y + acc[i][2] * a2v.z + acc[i][3] * a2v.w;
#pragma unroll
    for (int off = 16; off > 0; off >>= 1) {
      s1 += __shfl_down(s1, off, 32);
      s2 += __shfl_down(s2, off, 32);
    }
    if (cg == 0) {
      wh1[row0 + r0 + i] = s1 * LOG2E;
      wh2[row0 + r0 + i] = s2 * LOG2E;
    }
  }
}

// ---------------- kernel 2: adj-pack + attention partials + fused last-block combine ----------------
// Main loop byte-identical to the measured-best R9 structure (103 us). After storing its
// slab, the 8th-finishing block per row-group x combines the 8 slabs (L2-warm) inline.
// Release (writer threadfence before atomicAdd) + acquire (reader threadfence after flag)
// make the handoff agent-scope correct regardless of XCD placement (G16).
__global__ __launch_bounds__(256) void k_attn_p(const unsigned short* __restrict__ fragB,
                                                const int* __restrict__ adj,
                                                const float* __restrict__ wh1l,
                                                const float* __restrict__ wh2l,
                                                float* __restrict__ out_p,
                                                float* __restrict__ psum_p,
                                                float* __restrict__ out,
                                                int* __restrict__ cnt) {
  __shared__ char smask[64 * 136];
  __shared__ float invden[64];
  __shared__ int lastf;
  const int t = threadIdx.x;
  const int x = blockIdx.x;
  const int i0 = x * 64;
  const int jbase = blockIdx.y * 1024;    // ntiles = 16
  const int lane = t & 63, wv = t >> 6;
  const int ih = wv & 1, ch = wv >> 1;
  const int l15 = lane & 15, lg = lane >> 4;

  const int* abase = adj + (size_t)i0 * NV + jbase;

  // ---- phase 0: pack adj slice -> LDS bitmask (wave owns 16 rows, 4 KB sequential bursts) ----
  for (int rr = 0; rr < 16; ++rr) {
    const int r = wv * 16 + rr;
    const int* rp = abase + (size_t)r * NV + lane * 16;
    unsigned int m = 0;
#pragma unroll
    for (int p = 0; p < 4; ++p) {
      const int4 v = *(const int4*)(rp + p * 4);
      m |= ((unsigned)(v.x & 1) << (4 * p))     | ((unsigned)(v.y & 1) << (4 * p + 1)) |
           ((unsigned)(v.z & 1) << (4 * p + 2)) | ((unsigned)(v.w & 1) << (4 * p + 3));
    }
    *(unsigned short*)&smask[r * 136 + (lane >> 2) * 8 + (lane & 3) * 2] = (unsigned short)m;
  }
  __syncthreads();

  // ---- phase 1 (R9 main loop) ----
  const int rb = ih * 32;
  const float wh1a = wh1l[i0 + rb + l15];
  const float wh1b = wh1l[i0 + rb + 16 + l15];
  const char* mrowa = smask + (rb + l15) * 136;
  const char* mrowb = smask + (rb + 16 + l15) * 136;
  const unsigned short* bptr = fragB + (size_t)(jbase >> 6) * 8192 + ch * 4096 + lane * 8;
  const float* w2ptr = wh2l + jbase + lg * 8;

  f32x4 acc[2][4] = {};
  f32x4 accs[2] = {};
  short8 onesf;
#pragma unroll
  for (int e = 0; e < 8; ++e) onesf[e] = (short)0x3F80;  // bf16 1.0

  uint2 m2a = *(const uint2*)&mrowa[0];
  uint2 m2b = *(const uint2*)&mrowb[0];
  short8 bf[8];
#pragma unroll
  for (int ks = 0; ks < 2; ++ks)
#pragma unroll
    for (int cgl = 0; cgl < 4; ++cgl)
      bf[ks * 4 + cgl] = *(const short8*)(bptr + cgl * 1024 + ks * 512);
  bptr += 8192;

  for (int it = 0; it < 16; ++it) {
    const unsigned int m16a = ((m2a.x >> (8 * lg)) & 0xFFu) |
                              (((m2a.y >> (8 * lg)) & 0xFFu) << 8);
    const unsigned int m16b = ((m2b.x >> (8 * lg)) & 0xFFu) |
                              (((m2b.y >> (8 * lg)) & 0xFFu) << 8);
    const float4 wq0 = *(const float4*)(w2ptr);
    const float4 wq1 = *(const float4*)(w2ptr + 4);
    const float4 wq2 = *(const float4*)(w2ptr + 32);
    const float4 wq3 = *(const float4*)(w2ptr + 36);
    w2ptr += 64;

    short8 afa[2], afb[2];
#pragma unroll
    for (int ks = 0; ks < 2; ++ks) {
      const float4 wa = ks ? wq2 : wq0;
      const float4 wb = ks ? wq3 : wq1;
      const float w2v[8] = {wa.x, wa.y, wa.z, wa.w, wb.x, wb.y, wb.z, wb.w};
      union { short8 s8; unsigned int u[4]; } pka, pkb;
#pragma unroll
      for (int e = 0; e < 4; ++e) {
        const float x0 = wh1a + w2v[2 * e];
        const float x1 = wh1a + w2v[2 * e + 1];
        const float y0 = wh1b + w2v[2 * e];
        const float y1 = wh1b + w2v[2 * e + 1];
        const float lx0 = fmaxf(x0, 0.01f * x0);
        const float lx1 = fmaxf(x1, 0.01f * x1);
        const float ly0 = fmaxf(y0, 0.01f * y0);
        const float ly1 = fmaxf(y1, 0.01f * y1);
        float px0 = __builtin_amdgcn_exp2f(lx0);
        float px1 = __builtin_amdgcn_exp2f(lx1);
        float py0 = __builtin_amdgcn_exp2f(ly0);
        float py1 = __builtin_amdgcn_exp2f(ly1);
        px0 = ((m16a >> (ks * 8 + 2 * e)) & 1u) ? px0 : 0.f;
        px1 = ((m16a >> (ks * 8 + 2 * e + 1)) & 1u) ? px1 : 0.f;
        py0 = ((m16b >> (ks * 8 + 2 * e)) & 1u) ? py0 : 0.f;
        py1 = ((m16b >> (ks * 8 + 2 * e + 1)) & 1u) ? py1 : 0.f;
        pka.u[e] = pkbf2(px0, px1);
        pkb.u[e] = pkbf2(py0, py1);
      }
      afa[ks] = pka.s8;
      afb[ks] = pkb.s8;
    }
    if (it + 1 < 16) {
      m2a = *(const uint2*)&mrowa[(it + 1) * 8];
      m2b = *(const uint2*)&mrowb[(it + 1) * 8];
    }
#pragma unroll
    for (int ks = 0; ks < 2; ++ks) {
      acc[0][0] = __builtin_amdgcn_mfma_f32_16x16x32_bf16(afa[ks], bf[ks * 4 + 0], acc[0][0], 0, 0, 0);
      acc[0][1] = __builtin_amdgcn_mfma_f32_16x16x32_bf16(afa[ks], bf[ks * 4 + 1], acc[0][1], 0, 0, 0);
      acc[0][2] = __builtin_amdgcn_mfma_f32_16x16x32_bf16(afa[ks], bf[ks * 4 + 2], acc[0][2], 0, 0, 0);
      acc[0][3] = __builtin_amdgcn_mfma_f32_16x16x32_bf16(afa[ks], bf[ks * 4 + 3], acc[0][3], 0, 0, 0);
      accs[0]   = __builtin_amdgcn_mfma_f32_16x16x32_bf16(afa[ks], onesf, accs[0], 0, 0, 0);
      acc[1][0] = __builtin_amdgcn_mfma_f32_16x16x32_bf16(afb[ks], bf[ks * 4 + 0], acc[1][0], 0, 0, 0);
      acc[1][1] = __builtin_amdgcn_mfma_f32_16x16x32_bf16(afb[ks], bf[ks * 4 + 1], acc[1][1], 0, 0, 0);
      acc[1][2] = __builtin_amdgcn_mfma_f32_16x16x32_bf16(afb[ks], bf[ks * 4 + 2], acc[1][2], 0, 0, 0);
      acc[1][3] = __builtin_amdgcn_mfma_f32_16x16x32_bf16(afb[ks], bf[ks * 4 + 3], acc[1][3], 0, 0, 0);
      accs[1]   = __builtin_amdgcn_mfma_f32_16x16x32_bf16(afb[ks], onesf, accs[1], 0, 0, 0);
    }
    if (it + 1 < 16) {
#pragma unroll
      for (int ks = 0; ks < 2; ++ks)
#pragma unroll
        for (int cgl = 0; cgl < 4; ++cgl)
          bf[ks * 4 + cgl] = *(const short8*)(bptr + cgl * 1024 + ks * 512);
      bptr += 8192;
    }
  }

  // psum + partial stores (R9)
  if (ch == 0 && l15 == 0) {
#pragma unroll
    for (int rg = 0; rg < 2; ++rg)
#pragma unroll
      for (int r = 0; r < 4; ++r)
        psum_p[(size_t)blockIdx.y * NV + i0 + rb + rg * 16 + lg * 4 + r] = accs[rg][r];
  }
#pragma unroll
  for (int rg = 0; rg < 2; ++rg) {
    const size_t ob = ((size_t)blockIdx.y * NV + i0 + rb + rg * 16) * MOUT + ch * 64;
#pragma unroll
    for (int cgl = 0; cgl < 4; ++cgl)
#pragma unroll
      for (int r = 0; r < 4; ++r)
        out_p[ob + (size_t)(lg * 4 + r) * MOUT + cgl * 16 + l15] = acc[rg][cgl][r];
  }

  // ---- fused combine: 8th-finishing block for row-group x reduces slabs -> final out ----
  __syncthreads();
  if (t == 0) {
    __threadfence();                           // release: slab visible device-wide
    lastf = (atomicAdd(&cnt[x], 1) == 7);      // device-scope atomic (G12)
  }
  __syncthreads();
  if (!lastf) return;
  __threadfence();                             // acquire: see all 8 slabs (any XCD)

  if (t < 64) {
    float d = 0.f;
    for (int s = 0; s < 8; ++s) d += psum_p[(size_t)s * NV + i0 + t];
    invden[t] = 1.f / d;
  }
  __syncthreads();
#pragma unroll
  for (int k = 0; k < 8; ++k) {
    const int idx4 = k * 256 + t;              // float4 index in 64x128 tile
    const int row = idx4 >> 5, c4 = (idx4 & 31) * 4;
    float4 a = {0.f, 0.f, 0.f, 0.f};
    for (int s = 0; s < 8; ++s) {
      const float4 v = *(const float4*)&out_p[((size_t)s * NV + i0 + row) * MOUT + c4];
      a.x += v.x; a.y += v.y; a.z += v.z; a.w += v.w;
    }
    const float inv = invden[row];
    float4 o;
    o.x = elu1(a.x * inv);
    o.y = elu1(a.y * inv);
    o.z = elu1(a.z * inv);
    o.w = elu1(a.w * inv);
    *(float4*)&out[(size_t)(i0 + row) * MOUT + c4] = o;
  }
}

extern "C" void kernel_launch(void* const* d_in, const int* in_sizes, int n_in,
                              void* d_out, int out_size, void* d_ws, size_t ws_size,
                              hipStream_t stream) {
  const float* h  = (const float*)d_in[0];
  const int* adj  = (const int*)d_in[1];
  const float* w  = (const float*)d_in[2];
  const float* a1 = (const float*)d_in[3];
  const float* a2 = (const float*)d_in[4];
  float* out = (float*)d_out;

  char* ws = (char*)d_ws;
  // layout: [fragB 2MB][wh1 32KB][wh2 32KB][psum_p 256KB][cnt 1KB][out_p 8*4MB]
  unsigned short* fragB = (unsigned short*)ws;
  size_t off = (size_t)MOUT * NV * 2;
  float* wh1 = (float*)(ws + off); off += (size_t)NV * 4;
  float* wh2 = (float*)(ws + off); off += (size_t)NV * 4;
  float* psum_p = (float*)(ws + off); off += (size_t)8 * NV * 4;
  int* cnt = (int*)(ws + off); off += 1024;
  float* out_p = (float*)(ws + off);

  k_wh<<<NV / 16, 256, 0, stream>>>(h, w, a1, a2, fragB, wh1, wh2, cnt);
  k_attn_p<<<dim3(NV / 64, 8), 256, 0, stream>>>(fragB, adj, wh1, wh2, out_p, psum_p, out, cnt);
}

// Round 17
// 123.979 us; speedup vs baseline: 1.3918x; 1.3918x over previous
//
#include <hip/hip_runtime.h>
#include <hip/hip_bf16.h>
#include <cstdint>
#include <cstddef>

#define NV    8192   // nodes
#define KIN   512    // in features
#define MOUT  128    // out features
#define LOG2E 1.4426950408889634f

typedef __attribute__((ext_vector_type(4))) float f32x4;
typedef __attribute__((ext_vector_type(8))) short short8;

__device__ __forceinline__ float elu1(float x) { return x > 0.f ? x : expm1f(x); }

__device__ __forceinline__ unsigned int pkbf2(float a, float b) {
  union { __hip_bfloat162 h2; unsigned int u; } r;
  r.h2 = __float22bfloat162_rn(make_float2(a, b));
  return r.u;
}

// ---------------- kernel 1: wh1/wh2 (log2-scaled) + fragB (bf16, MFMA-fragment order) ----------------
// 16-row blocks (512 total, >=2/CU). fragB element (j=jt*64+ks*32+lg*8+e, c=cgf*16+l15).
// Correctness of the lg reduction (row0 & 31, NOT & 63) verified in R16 (absmax 2.4e-4).
__global__ __launch_bounds__(256) void k_wh(const float* __restrict__ h,
                                            const float* __restrict__ w,
                                            const float* __restrict__ a1,
                                            const float* __restrict__ a2,
                                            unsigned short* __restrict__ fragB,
                                            float* __restrict__ wh1,
                                            float* __restrict__ wh2) {
  __shared__ __align__(16) float hT[64][18];    // [k][row], 16 rows + 2 pad
  __shared__ __align__(16) float wT[64][128];   // [k][col]
  const int t = threadIdx.x;
  const int row0 = blockIdx.x * 16;
  const int hrow = t & 15, hkq = t >> 4;        // h-load: row, k-quad
  const int wc = t >> 1, whalf = t & 1;         // w-load
  const int cg = t & 31, rg = t >> 5;           // gemm: col-group(4), row-group(2)
  const int c0 = cg * 4, r0 = rg * 2;
  float acc[2][4] = {};

  for (int kt = 0; kt < 8; ++kt) {
    const int k0 = kt * 64;
    __syncthreads();
    {
      const float4 hv = *(const float4*)&h[(size_t)(row0 + hrow) * KIN + k0 + hkq * 4];
      hT[hkq * 4 + 0][hrow] = hv.x;
      hT[hkq * 4 + 1][hrow] = hv.y;
      hT[hkq * 4 + 2][hrow] = hv.z;
      hT[hkq * 4 + 3][hrow] = hv.w;
    }
#pragma unroll
    for (int mv = 0; mv < 8; ++mv) {
      const float4 wv4 = *(const float4*)&w[(size_t)wc * KIN + k0 + whalf * 32 + mv * 4];
      wT[whalf * 32 + mv * 4 + 0][wc] = wv4.x;
      wT[whalf * 32 + mv * 4 + 1][wc] = wv4.y;
      wT[whalf * 32 + mv * 4 + 2][wc] = wv4.z;
      wT[whalf * 32 + mv * 4 + 3][wc] = wv4.w;
    }
    __syncthreads();
#pragma unroll 8
    for (int kk = 0; kk < 64; ++kk) {
      const float2 hv = *(const float2*)&hT[kk][r0];
      const float4 wv4 = *(const float4*)&wT[kk][c0];
      const float hvv[2] = {hv.x, hv.y};
      const float wvv[4] = {wv4.x, wv4.y, wv4.z, wv4.w};
#pragma unroll
      for (int i = 0; i < 2; ++i)
#pragma unroll
        for (int j = 0; j < 4; ++j)
          acc[i][j] = fmaf(hvv[i], wvv[j], acc[i][j]);
    }
  }

  // fragB store straight from accumulators (see R16 derivation).
  {
    const size_t jt = (size_t)(row0 >> 6);
    const int ks = (row0 >> 5) & 1;
    const int lg = (((row0 & 31) + rg * 2) >> 3);   // 0..3
    const int cgf = cg >> 2;
    unsigned int* fB32 = (unsigned int*)fragB;
    const size_t ubase = (((jt * 8 + cgf) * 2 + ks) * 64 + lg * 16) * 4 + (rg & 3);
#pragma unroll
    for (int j = 0; j < 4; ++j) {
      const int l15 = (cg & 3) * 4 + j;
      fB32[ubase + (size_t)l15 * 4] = pkbf2(acc[0][j], acc[1][j]);
    }
  }

  const float4 a1v = *(const float4*)&a1[c0];
  const float4 a2v = *(const float4*)&a2[c0];
#pragma unroll
  for (int i = 0; i < 2; ++i) {
    float s1 = acc[i][0] * a1v.x + acc[i][1] * a1v.y + acc[i][2] * a1v.z + acc[i][3] * a1v.w;
    float s2 = acc[i][0] * a2v.x + acc[i][1] * a2v.y + acc[i][2] * a2v.z + acc[i][3] * a2v.w;
#pragma unroll
    for (int off = 16; off > 0; off >>= 1) {
      s1 += __shfl_down(s1, off, 32);
      s2 += __shfl_down(s2, off, 32);
    }
    if (cg == 0) {
      wh1[row0 + r0 + i] = s1 * LOG2E;
      wh2[row0 + r0 + i] = s2 * LOG2E;
    }
  }
}

// ---------------- kernel 2: adj-pack + attention partials (R9 structure, VERBATIM) ----------------
// The measured optimum across 16 rounds: 103 us, VGPR exactly 64 (the m69 occupancy cliff:
// 64 -> 8 waves/SIMD, 65+ -> 4). R16's fused combine (+12 VGPR) cost 80 us; do NOT add
// epilogue state to this kernel. grid (128,8); 64-row blocks; wave = 32 rows x 64 cols.
__global__ __launch_bounds__(256) void k_attn_p(const unsigned short* __restrict__ fragB,
                                                const int* __restrict__ adj,
                                                const float* __restrict__ wh1l,
                                                const float* __restrict__ wh2l,
                                                float* __restrict__ out_p,
                                                float* __restrict__ psum_p) {
  __shared__ char smask[64 * 136];
  const int t = threadIdx.x;
  const int i0 = blockIdx.x * 64;
  const int jbase = blockIdx.y * 1024;    // ntiles = 16
  const int lane = t & 63, wv = t >> 6;
  const int ih = wv & 1, ch = wv >> 1;
  const int l15 = lane & 15, lg = lane >> 4;

  const int* abase = adj + (size_t)i0 * NV + jbase;

  // ---- phase 0: pack adj slice -> LDS bitmask (wave owns 16 rows, 4 KB sequential bursts) ----
  for (int rr = 0; rr < 16; ++rr) {
    const int r = wv * 16 + rr;
    const int* rp = abase + (size_t)r * NV + lane * 16;
    unsigned int m = 0;
#pragma unroll
    for (int p = 0; p < 4; ++p) {
      const int4 v = *(const int4*)(rp + p * 4);
      m |= ((unsigned)(v.x & 1) << (4 * p))     | ((unsigned)(v.y & 1) << (4 * p + 1)) |
           ((unsigned)(v.z & 1) << (4 * p + 2)) | ((unsigned)(v.w & 1) << (4 * p + 3));
    }
    *(unsigned short*)&smask[r * 136 + (lane >> 2) * 8 + (lane & 3) * 2] = (unsigned short)m;
  }
  __syncthreads();

  // ---- phase 1 ----
  const int rb = ih * 32;
  const float wh1a = wh1l[i0 + rb + l15];
  const float wh1b = wh1l[i0 + rb + 16 + l15];
  const char* mrowa = smask + (rb + l15) * 136;
  const char* mrowb = smask + (rb + 16 + l15) * 136;
  const unsigned short* bptr = fragB + (size_t)(jbase >> 6) * 8192 + ch * 4096 + lane * 8;
  const float* w2ptr = wh2l + jbase + lg * 8;

  f32x4 acc[2][4] = {};
  f32x4 accs[2] = {};
  short8 onesf;
#pragma unroll
  for (int e = 0; e < 8; ++e) onesf[e] = (short)0x3F80;  // bf16 1.0

  uint2 m2a = *(const uint2*)&mrowa[0];
  uint2 m2b = *(const uint2*)&mrowb[0];
  short8 bf[8];
#pragma unroll
  for (int ks = 0; ks < 2; ++ks)
#pragma unroll
    for (int cgl = 0; cgl < 4; ++cgl)
      bf[ks * 4 + cgl] = *(const short8*)(bptr + cgl * 1024 + ks * 512);
  bptr += 8192;

  for (int it = 0; it < 16; ++it) {
    const unsigned int m16a = ((m2a.x >> (8 * lg)) & 0xFFu) |
                              (((m2a.y >> (8 * lg)) & 0xFFu) << 8);
    const unsigned int m16b = ((m2b.x >> (8 * lg)) & 0xFFu) |
                              (((m2b.y >> (8 * lg)) & 0xFFu) << 8);
    const float4 wq0 = *(const float4*)(w2ptr);
    const float4 wq1 = *(const float4*)(w2ptr + 4);
    const float4 wq2 = *(const float4*)(w2ptr + 32);
    const float4 wq3 = *(const float4*)(w2ptr + 36);
    w2ptr += 64;

    short8 afa[2], afb[2];
#pragma unroll
    for (int ks = 0; ks < 2; ++ks) {
      const float4 wa = ks ? wq2 : wq0;
      const float4 wb = ks ? wq3 : wq1;
      const float w2v[8] = {wa.x, wa.y, wa.z, wa.w, wb.x, wb.y, wb.z, wb.w};
      union { short8 s8; unsigned int u[4]; } pka, pkb;
#pragma unroll
      for (int e = 0; e < 4; ++e) {
        const float x0 = wh1a + w2v[2 * e];
        const float x1 = wh1a + w2v[2 * e + 1];
        const float y0 = wh1b + w2v[2 * e];
        const float y1 = wh1b + w2v[2 * e + 1];
        const float lx0 = fmaxf(x0, 0.01f * x0);
        const float lx1 = fmaxf(x1, 0.01f * x1);
        const float ly0 = fmaxf(y0, 0.01f * y0);
        const float ly1 = fmaxf(y1, 0.01f * y1);
        float px0 = __builtin_amdgcn_exp2f(lx0);
        float px1 = __builtin_amdgcn_exp2f(lx1);
        float py0 = __builtin_amdgcn_exp2f(ly0);
        float py1 = __builtin_amdgcn_exp2f(ly1);
        px0 = ((m16a >> (ks * 8 + 2 * e)) & 1u) ? px0 : 0.f;
        px1 = ((m16a >> (ks * 8 + 2 * e + 1)) & 1u) ? px1 : 0.f;
        py0 = ((m16b >> (ks * 8 + 2 * e)) & 1u) ? py0 : 0.f;
        py1 = ((m16b >> (ks * 8 + 2 * e + 1)) & 1u) ? py1 : 0.f;
        pka.u[e] = pkbf2(px0, px1);
        pkb.u[e] = pkbf2(py0, py1);
      }
      afa[ks] = pka.s8;
      afb[ks] = pkb.s8;
    }
    if (it + 1 < 16) {
      m2a = *(const uint2*)&mrowa[(it + 1) * 8];
      m2b = *(const uint2*)&mrowb[(it + 1) * 8];
    }
#pragma unroll
    for (int ks = 0; ks < 2; ++ks) {
      acc[0][0] = __builtin_amdgcn_mfma_f32_16x16x32_bf16(afa[ks], bf[ks * 4 + 0], acc[0][0], 0, 0, 0);
      acc[0][1] = __builtin_amdgcn_mfma_f32_16x16x32_bf16(afa[ks], bf[ks * 4 + 1], acc[0][1], 0, 0, 0);
      acc[0][2] = __builtin_amdgcn_mfma_f32_16x16x32_bf16(afa[ks], bf[ks * 4 + 2], acc[0][2], 0, 0, 0);
      acc[0][3] = __builtin_amdgcn_mfma_f32_16x16x32_bf16(afa[ks], bf[ks * 4 + 3], acc[0][3], 0, 0, 0);
      accs[0]   = __builtin_amdgcn_mfma_f32_16x16x32_bf16(afa[ks], onesf, accs[0], 0, 0, 0);
      acc[1][0] = __builtin_amdgcn_mfma_f32_16x16x32_bf16(afb[ks], bf[ks * 4 + 0], acc[1][0], 0, 0, 0);
      acc[1][1] = __builtin_amdgcn_mfma_f32_16x16x32_bf16(afb[ks], bf[ks * 4 + 1], acc[1][1], 0, 0, 0);
      acc[1][2] = __builtin_amdgcn_mfma_f32_16x16x32_bf16(afb[ks], bf[ks * 4 + 2], acc[1][2], 0, 0, 0);
      acc[1][3] = __builtin_amdgcn_mfma_f32_16x16x32_bf16(afb[ks], bf[ks * 4 + 3], acc[1][3], 0, 0, 0);
      accs[1]   = __builtin_amdgcn_mfma_f32_16x16x32_bf16(afb[ks], onesf, accs[1], 0, 0, 0);
    }
    if (it + 1 < 16) {
#pragma unroll
      for (int ks = 0; ks < 2; ++ks)
#pragma unroll
        for (int cgl = 0; cgl < 4; ++cgl)
          bf[ks * 4 + cgl] = *(const short8*)(bptr + cgl * 1024 + ks * 512);
      bptr += 8192;
    }
  }

  // psum via ones-column: lane(l15=0,lg) reg r holds rowsum[rg*16 + lg*4 + r]
  if (ch == 0 && l15 == 0) {
#pragma unroll
    for (int rg = 0; rg < 2; ++rg)
#pragma unroll
      for (int r = 0; r < 4; ++r)
        psum_p[(size_t)blockIdx.y * NV + i0 + rb + rg * 16 + lg * 4 + r] = accs[rg][r];
  }

  // unnormalized partial tiles (C/D: col=l15, row=lg*4+r)
#pragma unroll
  for (int rg = 0; rg < 2; ++rg) {
    const size_t ob = ((size_t)blockIdx.y * NV + i0 + rb + rg * 16) * MOUT + ch * 64;
#pragma unroll
    for (int cgl = 0; cgl < 4; ++cgl)
#pragma unroll
      for (int r = 0; r < 4; ++r)
        out_p[ob + (size_t)(lg * 4 + r) * MOUT + cgl * 16 + l15] = acc[rg][cgl][r];
  }
}

// ---------------- kernel 3: combine partials, normalize, ELU ----------------
__global__ __launch_bounds__(256) void k_comb(const float* __restrict__ out_p,
                                              const float* __restrict__ psum_p,
                                              float* __restrict__ out, int S) {
  const int idx = (blockIdx.x * 256 + threadIdx.x) * 4;
  const int n = idx >> 7;  // MOUT = 128
  float denom = 0.f;
  for (int s = 0; s < S; ++s) denom += psum_p[(size_t)s * NV + n];
  float4 acc = {0.f, 0.f, 0.f, 0.f};
  for (int s = 0; s < S; ++s) {
    const float4 v = *(const float4*)&out_p[(size_t)s * NV * MOUT + idx];
    acc.x += v.x; acc.y += v.y; acc.z += v.z; acc.w += v.w;
  }
  const float inv = 1.f / denom;
  float4 o;
  o.x = elu1(acc.x * inv);
  o.y = elu1(acc.y * inv);
  o.z = elu1(acc.z * inv);
  o.w = elu1(acc.w * inv);
  *(float4*)&out[idx] = o;
}

extern "C" void kernel_launch(void* const* d_in, const int* in_sizes, int n_in,
                              void* d_out, int out_size, void* d_ws, size_t ws_size,
                              hipStream_t stream) {
  const float* h  = (const float*)d_in[0];
  const int* adj  = (const int*)d_in[1];
  const float* w  = (const float*)d_in[2];
  const float* a1 = (const float*)d_in[3];
  const float* a2 = (const float*)d_in[4];
  float* out = (float*)d_out;

  char* ws = (char*)d_ws;
  // layout: [fragB 2MB][wh1 32KB][wh2 32KB][psum_p 256KB][out_p 8*4MB]
  unsigned short* fragB = (unsigned short*)ws;
  size_t off = (size_t)MOUT * NV * 2;
  float* wh1 = (float*)(ws + off); off += (size_t)NV * 4;
  float* wh2 = (float*)(ws + off); off += (size_t)NV * 4;
  float* psum_p = (float*)(ws + off); off += (size_t)8 * NV * 4;
  float* out_p = (float*)(ws + off);

  k_wh<<<NV / 16, 256, 0, stream>>>(h, w, a1, a2, fragB, wh1, wh2);
  k_attn_p<<<dim3(NV / 64, 8), 256, 0, stream>>>(fragB, adj, wh1, wh2, out_p, psum_p);
  k_comb<<<(NV * MOUT / 4) / 256, 256, 0, stream>>>(out_p, psum_p, out, 8);
}

// Round 18
// 121.893 us; speedup vs baseline: 1.4156x; 1.0171x over previous
//
#include <hip/hip_runtime.h>
#include <hip/hip_bf16.h>
#include <cstdint>
#include <cstddef>

#define NV    8192   // nodes
#define KIN   512    // in features
#define MOUT  128    // out features
#define LOG2E 1.4426950408889634f

typedef __attribute__((ext_vector_type(4))) float f32x4;
typedef __attribute__((ext_vector_type(8))) short short8;

__device__ __forceinline__ float elu1(float x) { return x > 0.f ? x : expm1f(x); }

__device__ __forceinline__ unsigned int pkbf2(float a, float b) {
  union { __hip_bfloat162 h2; unsigned int u; } r;
  r.h2 = __float22bfloat162_rn(make_float2(a, b));
  return r.u;
}

// ---------------- kernel 1: wh1/wh2 (log2-scaled) + fragB (bf16, MFMA-fragment order) ----------------
// 16-row blocks (512 total, >=2/CU). fragB element (j=jt*64+ks*32+lg*8+e, c=cgf*16+l15).
__global__ __launch_bounds__(256) void k_wh(const float* __restrict__ h,
                                            const float* __restrict__ w,
                                            const float* __restrict__ a1,
                                            const float* __restrict__ a2,
                                            unsigned short* __restrict__ fragB,
                                            float* __restrict__ wh1,
                                            float* __restrict__ wh2) {
  __shared__ __align__(16) float hT[64][18];    // [k][row], 16 rows + 2 pad
  __shared__ __align__(16) float wT[64][128];   // [k][col]
  const int t = threadIdx.x;
  const int row0 = blockIdx.x * 16;
  const int hrow = t & 15, hkq = t >> 4;        // h-load: row, k-quad
  const int wc = t >> 1, whalf = t & 1;         // w-load
  const int cg = t & 31, rg = t >> 5;           // gemm: col-group(4), row-group(2)
  const int c0 = cg * 4, r0 = rg * 2;
  float acc[2][4] = {};

  for (int kt = 0; kt < 8; ++kt) {
    const int k0 = kt * 64;
    __syncthreads();
    {
      const float4 hv = *(const float4*)&h[(size_t)(row0 + hrow) * KIN + k0 + hkq * 4];
      hT[hkq * 4 + 0][hrow] = hv.x;
      hT[hkq * 4 + 1][hrow] = hv.y;
      hT[hkq * 4 + 2][hrow] = hv.z;
      hT[hkq * 4 + 3][hrow] = hv.w;
    }
#pragma unroll
    for (int mv = 0; mv < 8; ++mv) {
      const float4 wv4 = *(const float4*)&w[(size_t)wc * KIN + k0 + whalf * 32 + mv * 4];
      wT[whalf * 32 + mv * 4 + 0][wc] = wv4.x;
      wT[whalf * 32 + mv * 4 + 1][wc] = wv4.y;
      wT[whalf * 32 + mv * 4 + 2][wc] = wv4.z;
      wT[whalf * 32 + mv * 4 + 3][wc] = wv4.w;
    }
    __syncthreads();
#pragma unroll 8
    for (int kk = 0; kk < 64; ++kk) {
      const float2 hv = *(const float2*)&hT[kk][r0];
      const float4 wv4 = *(const float4*)&wT[kk][c0];
      const float hvv[2] = {hv.x, hv.y};
      const float wvv[4] = {wv4.x, wv4.y, wv4.z, wv4.w};
#pragma unroll
      for (int i = 0; i < 2; ++i)
#pragma unroll
        for (int j = 0; j < 4; ++j)
          acc[i][j] = fmaf(hvv[i], wvv[j], acc[i][j]);
    }
  }

  // fragB store straight from accumulators (lg reduction modulo 32-row ks-block — R16 fix).
  {
    const size_t jt = (size_t)(row0 >> 6);
    const int ks = (row0 >> 5) & 1;
    const int lg = (((row0 & 31) + rg * 2) >> 3);   // 0..3
    const int cgf = cg >> 2;
    unsigned int* fB32 = (unsigned int*)fragB;
    const size_t ubase = (((jt * 8 + cgf) * 2 + ks) * 64 + lg * 16) * 4 + (rg & 3);
#pragma unroll
    for (int j = 0; j < 4; ++j) {
      const int l15 = (cg & 3) * 4 + j;
      fB32[ubase + (size_t)l15 * 4] = pkbf2(acc[0][j], acc[1][j]);
    }
  }

  const float4 a1v = *(const float4*)&a1[c0];
  const float4 a2v = *(const float4*)&a2[c0];
#pragma unroll
  for (int i = 0; i < 2; ++i) {
    float s1 = acc[i][0] * a1v.x + acc[i][1] * a1v.y + acc[i][2] * a1v.z + acc[i][3] * a1v.w;
    float s2 = acc[i][0] * a2v.x + acc[i][1] * a2v.y + acc[i][2] * a2v.z + acc[i][3] * a2v.w;
#pragma unroll
    for (int off = 16; off > 0; off >>= 1) {
      s1 += __shfl_down(s1, off, 32);
      s2 += __shfl_down(s2, off, 32);
    }
    if (cg == 0) {
      wh1[row0 + r0 + i] = s1 * LOG2E;
      wh2[row0 + r0 + i] = s2 * LOG2E;
    }
  }
}

// ---------------- kernel 2: adj-pack + attention partials (R9 structure, VERBATIM) ----------------
// Measured optimum across 17 rounds: ~103 us, VGPR exactly 64 (the occupancy cliff: 64 ->
// 8 waves/SIMD, 65+ -> 4; R16's +12-VGPR epilogue cost 80 us). Do NOT add state here.
__global__ __launch_bounds__(256) void k_attn_p(const unsigned short* __restrict__ fragB,
                                                const int* __restrict__ adj,
                                                const float* __restrict__ wh1l,
                                                const float* __restrict__ wh2l,
                                                float* __restrict__ out_p,
                                                float* __restrict__ psum_p) {
  __shared__ char smask[64 * 136];
  const int t = threadIdx.x;
  const int i0 = blockIdx.x * 64;
  const int jbase = blockIdx.y * 1024;    // ntiles = 16
  const int lane = t & 63, wv = t >> 6;
  const int ih = wv & 1, ch = wv >> 1;
  const int l15 = lane & 15, lg = lane >> 4;

  const int* abase = adj + (size_t)i0 * NV + jbase;

  // ---- phase 0: pack adj slice -> LDS bitmask (wave owns 16 rows, 4 KB sequential bursts) ----
  for (int rr = 0; rr < 16; ++rr) {
    const int r = wv * 16 + rr;
    const int* rp = abase + (size_t)r * NV + lane * 16;
    unsigned int m = 0;
#pragma unroll
    for (int p = 0; p < 4; ++p) {
      const int4 v = *(const int4*)(rp + p * 4);
      m |= ((unsigned)(v.x & 1) << (4 * p))     | ((unsigned)(v.y & 1) << (4 * p + 1)) |
           ((unsigned)(v.z & 1) << (4 * p + 2)) | ((unsigned)(v.w & 1) << (4 * p + 3));
    }
    *(unsigned short*)&smask[r * 136 + (lane >> 2) * 8 + (lane & 3) * 2] = (unsigned short)m;
  }
  __syncthreads();

  // ---- phase 1 ----
  const int rb = ih * 32;
  const float wh1a = wh1l[i0 + rb + l15];
  const float wh1b = wh1l[i0 + rb + 16 + l15];
  const char* mrowa = smask + (rb + l15) * 136;
  const char* mrowb = smask + (rb + 16 + l15) * 136;
  const unsigned short* bptr = fragB + (size_t)(jbase >> 6) * 8192 + ch * 4096 + lane * 8;
  const float* w2ptr = wh2l + jbase + lg * 8;

  f32x4 acc[2][4] = {};
  f32x4 accs[2] = {};
  short8 onesf;
#pragma unroll
  for (int e = 0; e < 8; ++e) onesf[e] = (short)0x3F80;  // bf16 1.0

  uint2 m2a = *(const uint2*)&mrowa[0];
  uint2 m2b = *(const uint2*)&mrowb[0];
  short8 bf[8];
#pragma unroll
  for (int ks = 0; ks < 2; ++ks)
#pragma unroll
    for (int cgl = 0; cgl < 4; ++cgl)
      bf[ks * 4 + cgl] = *(const short8*)(bptr + cgl * 1024 + ks * 512);
  bptr += 8192;

  for (int it = 0; it < 16; ++it) {
    const unsigned int m16a = ((m2a.x >> (8 * lg)) & 0xFFu) |
                              (((m2a.y >> (8 * lg)) & 0xFFu) << 8);
    const unsigned int m16b = ((m2b.x >> (8 * lg)) & 0xFFu) |
                              (((m2b.y >> (8 * lg)) & 0xFFu) << 8);
    const float4 wq0 = *(const float4*)(w2ptr);
    const float4 wq1 = *(const float4*)(w2ptr + 4);
    const float4 wq2 = *(const float4*)(w2ptr + 32);
    const float4 wq3 = *(const float4*)(w2ptr + 36);
    w2ptr += 64;

    short8 afa[2], afb[2];
#pragma unroll
    for (int ks = 0; ks < 2; ++ks) {
      const float4 wa = ks ? wq2 : wq0;
      const float4 wb = ks ? wq3 : wq1;
      const float w2v[8] = {wa.x, wa.y, wa.z, wa.w, wb.x, wb.y, wb.z, wb.w};
      union { short8 s8; unsigned int u[4]; } pka, pkb;
#pragma unroll
      for (int e = 0; e < 4; ++e) {
        const float x0 = wh1a + w2v[2 * e];
        const float x1 = wh1a + w2v[2 * e + 1];
        const float y0 = wh1b + w2v[2 * e];
        const float y1 = wh1b + w2v[2 * e + 1];
        const float lx0 = fmaxf(x0, 0.01f * x0);
        const float lx1 = fmaxf(x1, 0.01f * x1);
        const float ly0 = fmaxf(y0, 0.01f * y0);
        const float ly1 = fmaxf(y1, 0.01f * y1);
        float px0 = __builtin_amdgcn_exp2f(lx0);
        float px1 = __builtin_amdgcn_exp2f(lx1);
        float py0 = __builtin_amdgcn_exp2f(ly0);
        float py1 = __builtin_amdgcn_exp2f(ly1);
        px0 = ((m16a >> (ks * 8 + 2 * e)) & 1u) ? px0 : 0.f;
        px1 = ((m16a >> (ks * 8 + 2 * e + 1)) & 1u) ? px1 : 0.f;
        py0 = ((m16b >> (ks * 8 + 2 * e)) & 1u) ? py0 : 0.f;
        py1 = ((m16b >> (ks * 8 + 2 * e + 1)) & 1u) ? py1 : 0.f;
        pka.u[e] = pkbf2(px0, px1);
        pkb.u[e] = pkbf2(py0, py1);
      }
      afa[ks] = pka.s8;
      afb[ks] = pkb.s8;
    }
    if (it + 1 < 16) {
      m2a = *(const uint2*)&mrowa[(it + 1) * 8];
      m2b = *(const uint2*)&mrowb[(it + 1) * 8];
    }
#pragma unroll
    for (int ks = 0; ks < 2; ++ks) {
      acc[0][0] = __builtin_amdgcn_mfma_f32_16x16x32_bf16(afa[ks], bf[ks * 4 + 0], acc[0][0], 0, 0, 0);
      acc[0][1] = __builtin_amdgcn_mfma_f32_16x16x32_bf16(afa[ks], bf[ks * 4 + 1], acc[0][1], 0, 0, 0);
      acc[0][2] = __builtin_amdgcn_mfma_f32_16x16x32_bf16(afa[ks], bf[ks * 4 + 2], acc[0][2], 0, 0, 0);
      acc[0][3] = __builtin_amdgcn_mfma_f32_16x16x32_bf16(afa[ks], bf[ks * 4 + 3], acc[0][3], 0, 0, 0);
      accs[0]   = __builtin_amdgcn_mfma_f32_16x16x32_bf16(afa[ks], onesf, accs[0], 0, 0, 0);
      acc[1][0] = __builtin_amdgcn_mfma_f32_16x16x32_bf16(afb[ks], bf[ks * 4 + 0], acc[1][0], 0, 0, 0);
      acc[1][1] = __builtin_amdgcn_mfma_f32_16x16x32_bf16(afb[ks], bf[ks * 4 + 1], acc[1][1], 0, 0, 0);
      acc[1][2] = __builtin_amdgcn_mfma_f32_16x16x32_bf16(afb[ks], bf[ks * 4 + 2], acc[1][2], 0, 0, 0);
      acc[1][3] = __builtin_amdgcn_mfma_f32_16x16x32_bf16(afb[ks], bf[ks * 4 + 3], acc[1][3], 0, 0, 0);
      accs[1]   = __builtin_amdgcn_mfma_f32_16x16x32_bf16(afb[ks], onesf, accs[1], 0, 0, 0);
    }
    if (it + 1 < 16) {
#pragma unroll
      for (int ks = 0; ks < 2; ++ks)
#pragma unroll
        for (int cgl = 0; cgl < 4; ++cgl)
          bf[ks * 4 + cgl] = *(const short8*)(bptr + cgl * 1024 + ks * 512);
      bptr += 8192;
    }
  }

  // psum via ones-column: lane(l15=0,lg) reg r holds rowsum[rg*16 + lg*4 + r]
  if (ch == 0 && l15 == 0) {
#pragma unroll
    for (int rg = 0; rg < 2; ++rg)
#pragma unroll
      for (int r = 0; r < 4; ++r)
        psum_p[(size_t)blockIdx.y * NV + i0 + rb + rg * 16 + lg * 4 + r] = accs[rg][r];
  }

  // unnormalized partial tiles (C/D: col=l15, row=lg*4+r)
#pragma unroll
  for (int rg = 0; rg < 2; ++rg) {
    const size_t ob = ((size_t)blockIdx.y * NV + i0 + rb + rg * 16) * MOUT + ch * 64;
#pragma unroll
    for (int cgl = 0; cgl < 4; ++cgl)
#pragma unroll
      for (int r = 0; r < 4; ++r)
        out_p[ob + (size_t)(lg * 4 + r) * MOUT + cgl * 16 + l15] = acc[rg][cgl][r];
  }
}

// ---------------- kernel 3: combine partials, normalize, ELU (S=8 hardcoded, full MLP) ----------------
// R17's version took a runtime S -> slab loops couldn't unroll -> serialized slab streams
// (2.6 TB/s realized). Hardcoding 8 + full unroll issues all 8 out_p loads + 8 psum loads
// independently (Guideline 7: ILP). Memory-bound; VGPR ~60 is harmless here.
__global__ __launch_bounds__(256) void k_comb(const float* __restrict__ out_p,
                                              const float* __restrict__ psum_p,
                                              float* __restrict__ out) {
  const int idx = (blockIdx.x * 256 + threadIdx.x) * 4;
  const int n = idx >> 7;  // MOUT = 128
  float4 v[8];
#pragma unroll
  for (int s = 0; s < 8; ++s)
    v[s] = *(const float4*)&out_p[(size_t)s * NV * MOUT + idx];
  float ds[8];
#pragma unroll
  for (int s = 0; s < 8; ++s)
    ds[s] = psum_p[(size_t)s * NV + n];

  const float denom = ((ds[0] + ds[1]) + (ds[2] + ds[3])) +
                      ((ds[4] + ds[5]) + (ds[6] + ds[7]));
  float4 a;
  a.x = ((v[0].x + v[1].x) + (v[2].x + v[3].x)) + ((v[4].x + v[5].x) + (v[6].x + v[7].x));
  a.y = ((v[0].y + v[1].y) + (v[2].y + v[3].y)) + ((v[4].y + v[5].y) + (v[6].y + v[7].y));
  a.z = ((v[0].z + v[1].z) + (v[2].z + v[3].z)) + ((v[4].z + v[5].z) + (v[6].z + v[7].z));
  a.w = ((v[0].w + v[1].w) + (v[2].w + v[3].w)) + ((v[4].w + v[5].w) + (v[6].w + v[7].w));

  const float inv = 1.f / denom;
  float4 o;
  o.x = elu1(a.x * inv);
  o.y = elu1(a.y * inv);
  o.z = elu1(a.z * inv);
  o.w = elu1(a.w * inv);
  *(float4*)&out[idx] = o;
}

extern "C" void kernel_launch(void* const* d_in, const int* in_sizes, int n_in,
                              void* d_out, int out_size, void* d_ws, size_t ws_size,
                              hipStream_t stream) {
  const float* h  = (const float*)d_in[0];
  const int* adj  = (const int*)d_in[1];
  const float* w  = (const float*)d_in[2];
  const float* a1 = (const float*)d_in[3];
  const float* a2 = (const float*)d_in[4];
  float* out = (float*)d_out;

  char* ws = (char*)d_ws;
  // layout: [fragB 2MB][wh1 32KB][wh2 32KB][psum_p 256KB][out_p 8*4MB]
  unsigned short* fragB = (unsigned short*)ws;
  size_t off = (size_t)MOUT * NV * 2;
  float* wh1 = (float*)(ws + off); off += (size_t)NV * 4;
  float* wh2 = (float*)(ws + off); off += (size_t)NV * 4;
  float* psum_p = (float*)(ws + off); off += (size_t)8 * NV * 4;
  float* out_p = (float*)(ws + off);

  k_wh<<<NV / 16, 256, 0, stream>>>(h, w, a1, a2, fragB, wh1, wh2);
  k_attn_p<<<dim3(NV / 64, 8), 256, 0, stream>>>(fragB, adj, wh1, wh2, out_p, psum_p);
  k_comb<<<(NV * MOUT / 4) / 256, 256, 0, stream>>>(out_p, psum_p, out);
}